// Round 9
// baseline (111.071 us; speedup 1.0000x reference)
//
#include <hip/hip_runtime.h>
#include <hip/hip_fp16.h>
#include <hip/hip_cooperative_groups.h>
#include <cmath>

namespace cg = cooperative_groups;

#define NBINS   84
#define NFRAMES 256
#define HOP     1024
#define NB      8            // nb_samples * nb_channels
#define KP      960          // padded K (columns of A / rows of B)
#define KPH     (KP/2)       // 480 column pairs (cos,sin)
#define GBLK    278          // number of 1024-sample output blocks
#define MROWS   (GBLK*NB)    // 2224 real rows
#define MPAD    2240         // 35*64
#define SD      23           // d-slices: max ceil(L/1024)

#define GRID_BLKS 560        // 35 m-tiles x 16 n-tiles
#define NTHREADS  (GRID_BLKS*256)

typedef _Float16 f16x8 __attribute__((ext_vector_type(8)));
typedef float    f32x4 __attribute__((ext_vector_type(4)));

struct CqtArgs {
    int   wl[NBINS];            // per-bin window length (descending)
    float omega[NBINS];         // 2*pi*f/SR
    float invL[NBINS];          // 1/wl
    int   Ktot;
    unsigned short ct[KP];      // col -> k | d<<7 | c<<12 ; 0xFFFF = pad
};

// ---------------- builders (grid-stride; used by coop kernel) ----------------
__device__ __forceinline__ void build_all(unsigned short* __restrict__ Am,
                                          unsigned short* __restrict__ Bt,
                                          float* __restrict__ S,
                                          const float* __restrict__ X,
                                          const CqtArgs& a, int gtid) {
    const float TWOPI = 6.28318530717958647692f;
    // Bt[r][2j]=cos*hann, Bt[r][2j+1]=sin*hann; t = 1024 d + r
    for (int i = gtid; i < 1024 * KPH; i += NTHREADS) {
        const int r = i / KPH, j = i - r * KPH;
        unsigned int pack = 0;
        const unsigned short rec = a.ct[2 * j];
        if (rec != 0xFFFF) {
            const int k = rec & 0x7F, d = (rec >> 7) & 0x1F;
            const int t = (d << 10) + r;
            if (t < a.wl[k]) {
                const float tf = (float)t;
                const float w  = 0.5f - 0.5f * cosf(TWOPI * tf * a.invL[k]);
                float s, c;
                sincosf(a.omega[k] * tf, &s, &c);
                pack = (unsigned int)__half_as_ushort(__float2half(c * w))
                     | ((unsigned int)__half_as_ushort(__float2half(s * w)) << 16);
            }
        }
        *(unsigned int*)(Bt + (size_t)r * KP + 2 * j) = pack;
    }
    // A[row=(g*8+b)][2j] = Re X[b,k,g-d], [2j+1] = -Im X[b,k,g-d]
    for (int i = gtid; i < MPAD * KPH; i += NTHREADS) {
        const int row = i / KPH, j = i - row * KPH;
        unsigned int pack = 0;
        const unsigned short rec = a.ct[2 * j];
        if (row < MROWS && rec != 0xFFFF) {
            const int k = rec & 0x7F, d = (rec >> 7) & 0x1F;
            const int g = row >> 3, b = row & 7;
            const int f = g - d;
            if (f >= 0 && f < NFRAMES) {
                const float2 x = *(const float2*)(X + (((size_t)b * NBINS + k) * NFRAMES + f) * 2);
                pack = (unsigned int)__half_as_ushort(__float2half(x.x))
                     | ((unsigned int)__half_as_ushort(__float2half(-x.y)) << 16);
            }
        }
        *(unsigned int*)(Am + (size_t)row * KP + 2 * j) = pack;
    }
    // S[t] = sum_k [t < wl_k] hann_k(t)^2 ; wl descending -> break at first fail
    for (int t = gtid; t < SD * 1024; t += NTHREADS) {
        float sum = 0.f;
        for (int k = 0; k < NBINS; ++k) {
            if (t >= a.wl[k]) break;
            const float w = 0.5f - 0.5f * cosf(TWOPI * (float)t * a.invL[k]);
            sum += w * w;
        }
        S[t] = sum;
    }
}

// inverse norm: direct positive-term sum over d = max(0,g-255) .. min(g,22)
__device__ __forceinline__ float inv_norm(const float* __restrict__ S, int g, int ncol) {
    if (g >= GBLK) return 1.0f;
    const int lo = (g > NFRAMES - 1) ? (g - (NFRAMES - 1)) : 0;
    const int hi = g < (SD - 1) ? g : (SD - 1);
    float s = 0.f;
    for (int d = lo; d <= hi; ++d) s += S[(d << 10) + ncol];
    return (s > 1e-10f) ? 1.0f / s : 1.0f;
}

// ---------------- GEMM body (one 64x64 tile; identical numerics to R8) ------
__device__ __forceinline__ void gemm_body(const unsigned short* __restrict__ Am,
                                          const unsigned short* __restrict__ Bt,
                                          const float* __restrict__ S,
                                          float* __restrict__ out, int length,
                                          int bm, int bn) {
    __shared__ __align__(16) char lds[16384];
    const int tid = threadIdx.x;
    const int l   = tid & 63;
    const int wid = tid >> 6;
    const int wm  = wid >> 1, wn = wid & 1;

    const int q0 = tid,      q1 = tid + 256;
    const int r0 = q0 >> 3,  c0 = q0 & 7, s0 = c0 ^ (r0 & 7);
    const int r1 = q1 >> 3,  c1 = q1 & 7, s1 = c1 ^ (r1 & 7);

    const char* gA = (const char*)Am + (size_t)(bm * 64) * KP * 2;
    const char* gB = (const char*)Bt + (size_t)(bn * 64) * KP * 2;
    const char* gA0 = gA + ((size_t)r0 * KP + s0 * 8) * 2;
    const char* gA1 = gA + ((size_t)r1 * KP + s1 * 8) * 2;
    const char* gB0 = gB + ((size_t)r0 * KP + s0 * 8) * 2;
    const char* gB1 = gB + ((size_t)r1 * KP + s1 * 8) * 2;
    char* lA = lds;
    char* lB = lds + 8192;

    f32x4 acc00 = {0.f,0.f,0.f,0.f}, acc01 = {0.f,0.f,0.f,0.f};
    f32x4 acc10 = {0.f,0.f,0.f,0.f}, acc11 = {0.f,0.f,0.f,0.f};

    f16x8 ra0 = *(const f16x8*)(gA0);
    f16x8 ra1 = *(const f16x8*)(gA1);
    f16x8 rb0 = *(const f16x8*)(gB0);
    f16x8 rb1 = *(const f16x8*)(gB1);

    const int arow0 = wm * 32 + (l & 15), arow1 = arow0 + 16;
    const int brow0 = wn * 32 + (l & 15), brow1 = brow0 + 16;
    const int kq = l >> 4;

    for (int kk = 0; kk < KP; kk += 64) {
        __syncthreads();
        *(f16x8*)(lA + q0 * 16) = ra0;
        *(f16x8*)(lA + q1 * 16) = ra1;
        *(f16x8*)(lB + q0 * 16) = rb0;
        *(f16x8*)(lB + q1 * 16) = rb1;
        __syncthreads();
        if (kk + 64 < KP) {
            ra0 = *(const f16x8*)(gA0 + (kk + 64) * 2);
            ra1 = *(const f16x8*)(gA1 + (kk + 64) * 2);
            rb0 = *(const f16x8*)(gB0 + (kk + 64) * 2);
            rb1 = *(const f16x8*)(gB1 + (kk + 64) * 2);
        }
#pragma unroll
        for (int ks = 0; ks < 2; ++ks) {
            const int kb = ks * 4 + kq;
            f16x8 a0 = *(const f16x8*)(lA + arow0 * 128 + ((kb ^ (arow0 & 7)) << 4));
            f16x8 a1 = *(const f16x8*)(lA + arow1 * 128 + ((kb ^ (arow1 & 7)) << 4));
            f16x8 b0 = *(const f16x8*)(lB + brow0 * 128 + ((kb ^ (brow0 & 7)) << 4));
            f16x8 b1 = *(const f16x8*)(lB + brow1 * 128 + ((kb ^ (brow1 & 7)) << 4));
            acc00 = __builtin_amdgcn_mfma_f32_16x16x32_f16(a0, b0, acc00, 0, 0, 0);
            acc01 = __builtin_amdgcn_mfma_f32_16x16x32_f16(a0, b1, acc01, 0, 0, 0);
            acc10 = __builtin_amdgcn_mfma_f32_16x16x32_f16(a1, b0, acc10, 0, 0, 0);
            acc11 = __builtin_amdgcn_mfma_f32_16x16x32_f16(a1, b1, acc11, 0, 0, 0);
        }
    }

    const int mbase = bm * 64 + wm * 32;
    const int nbase = bn * 64 + wn * 32;
    const int ncol0 = nbase + (l & 15);
    const int ncol1 = ncol0 + 16;
    const int g0    = (mbase >> 3) + (kq >> 1);
    const float inv00 = inv_norm(S, g0,     ncol0);
    const float inv01 = inv_norm(S, g0,     ncol1);
    const float inv10 = inv_norm(S, g0 + 2, ncol0);
    const float inv11 = inv_norm(S, g0 + 2, ncol1);

#pragma unroll
    for (int mi = 0; mi < 2; ++mi) {
#pragma unroll
        for (int ni = 0; ni < 2; ++ni) {
            f32x4 v = (mi == 0) ? ((ni == 0) ? acc00 : acc01)
                                : ((ni == 0) ? acc10 : acc11);
            const float invv = (mi == 0) ? ((ni == 0) ? inv00 : inv01)
                                         : ((ni == 0) ? inv10 : inv11);
            const int ncol = (ni == 0) ? ncol0 : ncol1;
#pragma unroll
            for (int reg = 0; reg < 4; ++reg) {
                const int mrow = mbase + mi * 16 + kq * 4 + reg;
                if (mrow < MROWS) {
                    const int g = mrow >> 3, b = mrow & 7;
                    const int p = (g << 10) + ncol;
                    if (p < length)
                        out[(size_t)b * length + p] = v[reg] * invv;
                }
            }
        }
    }
}

// ---------------- single cooperative kernel: build -> grid.sync -> GEMM -----
__global__ __launch_bounds__(256, 3)
void icqt_coop(unsigned short* __restrict__ Am, unsigned short* __restrict__ Bt,
               float* __restrict__ S, const float* __restrict__ X,
               float* __restrict__ out, int length, CqtArgs a) {
    build_all(Am, Bt, S, X, a, blockIdx.x * 256 + threadIdx.x);
    cg::this_grid().sync();
    gemm_body(Am, Bt, S, out, length, blockIdx.x >> 4, blockIdx.x & 15);
}

// ---------------- fallback 2-kernel path (R8-proven) -------------------------
__global__ __launch_bounds__(256)
void mega_build(unsigned short* __restrict__ Am, unsigned short* __restrict__ Bt,
                float* __restrict__ S, const float* __restrict__ X, CqtArgs a) {
    build_all(Am, Bt, S, X, a, blockIdx.x * 256 + threadIdx.x);
}

__global__ __launch_bounds__(256)
void gemm_icqt(const unsigned short* __restrict__ Am, const unsigned short* __restrict__ Bt,
               const float* __restrict__ S, float* __restrict__ out, int length) {
    gemm_body(Am, Bt, S, out, length, blockIdx.x, blockIdx.y);
}

// Last-resort fallback (ws too small): on-the-fly trig gather.
__global__ void icqt_gather_fallback(const float* __restrict__ X, float* __restrict__ out,
                                     CqtArgs a, int length) {
    const int p = blockIdx.x * blockDim.x + threadIdx.x;
    if (p >= length) return;
    float acc[NB];
#pragma unroll
    for (int b = 0; b < NB; ++b) acc[b] = 0.0f;
    float nrm = 0.0f;
    int fhi = p >> 10;
    if (fhi > NFRAMES - 1) fhi = NFRAMES - 1;
    const float2* X2 = reinterpret_cast<const float2*>(X);
    for (int k = 0; k < NBINS; ++k) {
        const int L = a.wl[k];
        int flo = (p - L + HOP) >> 10;
        if (flo < 0) flo = 0;
        for (int f = flo; f <= fhi; ++f) {
            const int t = p - (f << 10);
            if (t < L) {
                float tf = (float)t;
                float ang = a.omega[k] * tf;
                float s = sinf(ang), c = cosf(ang);
                float w = 0.5f - 0.5f * cosf(6.28318530717958647692f * tf * a.invL[k]);
                float bre = c * w, bim = s * w;
                nrm += w * w;
                const int base = k * NFRAMES + f;
#pragma unroll
                for (int b = 0; b < NB; ++b) {
                    float2 cv = X2[(size_t)b * (NBINS * NFRAMES) + base];
                    acc[b] += cv.x * bre - cv.y * bim;
                }
            }
        }
    }
    const float inv = 1.0f / ((nrm > 1e-10f) ? nrm : 1.0f);
#pragma unroll
    for (int b = 0; b < NB; ++b)
        out[(size_t)b * length + p] = acc[b] * inv;
}

extern "C" void kernel_launch(void* const* d_in, const int* in_sizes, int n_in,
                              void* d_out, int out_size, void* d_ws, size_t ws_size,
                              hipStream_t stream) {
    // Host geometry (deterministic; np.round = banker's via nearbyint)
    CqtArgs a;
    int cb[NBINS];
    const double SR = 44100.0;
    const double Q  = 1.0 / (std::exp2(1.0 / 12.0) - 1.0);
    int Ktot = 0;
    for (int k = 0; k < NBINS; ++k) {
        double f = 32.7 * std::exp2((double)k / 12.0);
        int L = (int)std::nearbyint(Q * SR / f);
        a.wl[k]    = L;
        cb[k]      = Ktot;
        a.omega[k] = (float)(2.0 * 3.14159265358979323846 * f / SR);
        a.invL[k]  = (float)(1.0 / (double)L);
        Ktot += 2 * ((L + 1023) / 1024);
    }
    a.Ktot = Ktot;
    for (int col = 0; col < KP; ++col) a.ct[col] = 0xFFFF;
    if (Ktot <= KP) {
        for (int k = 0; k < NBINS; ++k) {
            const int D2 = 2 * ((a.wl[k] + 1023) / 1024);
            for (int j = 0; j < D2; ++j)
                a.ct[cb[k] + j] = (unsigned short)(k | ((j >> 1) << 7) | ((j & 1) << 12));
        }
    }

    const int length = out_size / NB;            // 283800
    const float* X = (const float*)d_in[0];
    float* out     = (float*)d_out;

    // ws layout (16B-aligned by construction)
    const size_t offA = 0;
    const size_t szA  = (size_t)MPAD * KP * 2;           // 4,300,800
    const size_t offB = offA + szA;
    const size_t szB  = (size_t)1024 * KP * 2;           // 1,966,080
    const size_t offS = offB + szB;
    const size_t szS  = (size_t)SD * 1024 * 4;           //    94,208
    const size_t need = offS + szS;

    if (Ktot > KP || a.wl[0] > SD * 1024 || ws_size < need) {
        const int blocks = (length + 255) / 256;
        icqt_gather_fallback<<<blocks, 256, 0, stream>>>(X, out, a, length);
        return;
    }

    unsigned short* Am = (unsigned short*)((char*)d_ws + offA);
    unsigned short* Bt = (unsigned short*)((char*)d_ws + offB);
    float*          S  = (float*)((char*)d_ws + offS);

    int len_ = length;
    void* kargs[] = { (void*)&Am, (void*)&Bt, (void*)&S, (void*)&X,
                      (void*)&out, (void*)&len_, (void*)&a };
    hipError_t ce = hipLaunchCooperativeKernel(icqt_coop, dim3(GRID_BLKS), dim3(256),
                                               kargs, 0, stream);
    if (ce != hipSuccess) {
        (void)hipGetLastError();   // clear sticky error; fall back to 2-kernel path
        mega_build<<<dim3((MPAD * KPH + 255) / 256 > 0 ? 6620 : 6620), 256, 0, stream>>>(Am, Bt, S, X, a);
        gemm_icqt<<<dim3(MPAD / 64, 1024 / 64), 256, 0, stream>>>(Am, Bt, S, out, length);
    }
}

// Round 10
// 68.604 us; speedup vs baseline: 1.6190x; 1.6190x over previous
//
#include <hip/hip_runtime.h>
#include <hip/hip_fp16.h>
#include <cmath>

#define NBINS   84
#define NFRAMES 256
#define HOP     1024
#define NB      8            // nb_samples * nb_channels
#define KP      960          // padded K (f16 columns of A / rows of B)
#define KPH     (KP/2)       // 480 column pairs (cos,sin)
#define KPQ     (KP/8)       // 120 quads (4 pairs) per row
#define GBLK    278          // number of 1024-sample output blocks
#define MROWS   (GBLK*NB)    // 2224 real rows
#define MPAD    2240         // 35*64
#define SD      23           // d-slices: max ceil(L/1024)

// builder regions (blocks of 256 threads)
#define BT_BLOCKS  480           // 1024 r x 120 quads / 256
#define S_BLOCKS   92            // 23*1024/256 : S[t] window-energy table
#define ALL_BLOCKS (BT_BLOCKS + S_BLOCKS)

typedef _Float16 f16x8 __attribute__((ext_vector_type(8)));
typedef float    f32x4 __attribute__((ext_vector_type(4)));

struct alignas(16) CqtArgs {
    unsigned short ct[KP];      // FIRST member, 16B-aligned: col -> k|d<<7|c<<12; 0xFFFF pad
    int   wl[NBINS];            // per-bin window length (descending)
    float omega[NBINS];         // 2*pi*f/SR
    float invL[NBINS];          // 1/wl
    int   Ktot;
};

// ---------------- slim builder: Bt (vectorized 4 pairs/thread) + S[t] --------
__global__ __launch_bounds__(256)
void build_bt_s(unsigned short* __restrict__ Bt, float* __restrict__ S, CqtArgs a) {
    const int blk = blockIdx.x;
    const int tid = threadIdx.x;
    const float TWOPI = 6.28318530717958647692f;

    if (blk < BT_BLOCKS) {
        // thread -> (r, quad): 4 consecutive (cos,sin) pairs -> one 16B store
        const int idx  = blk * 256 + tid;        // < 1024*120
        const int r    = idx / KPQ;
        const int quad = idx - r * KPQ;
        const int jb   = quad * 4;
        const uint4 rr = *(const uint4*)(&a.ct[2 * jb]);  // 4 even records (lo halves)
        const unsigned int recs[4] = { rr.x & 0xFFFFu, rr.y & 0xFFFFu,
                                       rr.z & 0xFFFFu, rr.w & 0xFFFFu };
        f16x8 v;
#pragma unroll
        for (int jj = 0; jj < 4; ++jj) {
            float vc = 0.f, vs = 0.f;
            const unsigned int rec = recs[jj];
            if (rec != 0xFFFFu) {
                const int k = rec & 0x7F, d = (rec >> 7) & 0x1F;
                const int t = (d << 10) + r;
                if (t < a.wl[k]) {
                    const float tf = (float)t;
                    const float w  = 0.5f - 0.5f * cosf(TWOPI * tf * a.invL[k]);
                    float s, c;
                    sincosf(a.omega[k] * tf, &s, &c);
                    vc = c * w; vs = s * w;
                }
            }
            v[2 * jj]     = (_Float16)vc;
            v[2 * jj + 1] = (_Float16)vs;
        }
        *(f16x8*)(Bt + (size_t)r * KP + 8 * quad) = v;
    } else {
        // S[t] = sum_k [t < wl_k] hann_k(t)^2 ; wl descending -> break at first fail
        const int t = (blk - BT_BLOCKS) * 256 + tid;   // t < 23552
        float sum = 0.f;
        for (int k = 0; k < NBINS; ++k) {
            if (t >= a.wl[k]) break;
            const float w = 0.5f - 0.5f * cosf(TWOPI * (float)t * a.invL[k]);
            sum += w * w;
        }
        S[t] = sum;
    }
}

// inverse norm: direct positive-term sum over d = max(0,g-255) .. min(g,22)
__device__ __forceinline__ float inv_norm(const float* __restrict__ S, int g, int ncol) {
    if (g >= GBLK) return 1.0f;
    const int lo = (g > NFRAMES - 1) ? (g - (NFRAMES - 1)) : 0;
    const int hi = g < (SD - 1) ? g : (SD - 1);
    float s = 0.f;
    for (int d = lo; d <= hi; ++d) s += S[(d << 10) + ncol];
    return (s > 1e-10f) ? 1.0f / s : 1.0f;
}

// Implicit-im2col A-fragment gather: f16 cols [2*jgbase, 2*jgbase+8) of row mrow.
// A[row=(g*8+b)][2j] = Re X[b,k,g-d], [2j+1] = -Im X[b,k,g-d]; zeros for pad/OOB.
__device__ __forceinline__ f16x8 gather_A(const float2* __restrict__ X2,
                                          const CqtArgs& a, int mrow, int jgbase) {
    const int g = mrow >> 3, b = mrow & 7;
    const bool rowok = (mrow < MROWS);
    const uint4 rr = *(const uint4*)(&a.ct[2 * jgbase]);   // 4 even records, 16B aligned
    const unsigned int recs[4] = { rr.x & 0xFFFFu, rr.y & 0xFFFFu,
                                   rr.z & 0xFFFFu, rr.w & 0xFFFFu };
    f16x8 v;
#pragma unroll
    for (int jj = 0; jj < 4; ++jj) {
        float re = 0.f, nim = 0.f;
        const unsigned int rec = recs[jj];
        const int k = rec & 0x7F, d = (rec >> 7) & 0x1F;
        const int f = g - d;
        if (rowok && rec != 0xFFFFu && f >= 0 && f < NFRAMES) {
            const float2 x = X2[((size_t)b * NBINS + k) * NFRAMES + f];
            re = x.x; nim = -x.y;
        }
        v[2 * jj]     = (_Float16)re;
        v[2 * jj + 1] = (_Float16)nim;
    }
    return v;
}

// GEMM: C[M=2240][N=1024] = A[M][K=960] * Bt[N][K]^T, f16 in / f32 acc.
// A is gathered from X on the fly (no materialized A); B panels read from Bt.
// 64x64 tile, 4 waves (2x2), each wave 32x32 via 2x2 mfma_f32_16x16x32_f16.
// LDS chunk-XOR swizzle (T2); next-K A-gather + B-loads issued in MFMA shadow.
__global__ __launch_bounds__(256)
void gemm_icqt(const float2* __restrict__ X2, const unsigned short* __restrict__ Bt,
               const float* __restrict__ S, float* __restrict__ out, int length,
               CqtArgs a) {
    __shared__ __align__(16) char lds[16384];
    const int tid = threadIdx.x;
    const int l   = tid & 63;
    const int wid = tid >> 6;
    const int wm  = wid >> 1, wn = wid & 1;
    const int bm  = blockIdx.x, bn = blockIdx.y;

    // staging: 512 16B-chunks per 64x64 f16 tile; thread covers q0=tid, q1=tid+256
    const int q0 = tid,      q1 = tid + 256;
    const int r0 = q0 >> 3,  c0 = q0 & 7, s0 = c0 ^ (r0 & 7);
    const int r1 = q1 >> 3,  c1 = q1 & 7, s1 = c1 ^ (r1 & 7);

    const int mrow0 = bm * 64 + r0;
    const int mrow1 = bm * 64 + r1;

    const char* gB = (const char*)Bt + (size_t)(bn * 64) * KP * 2;
    const char* gB0 = gB + ((size_t)r0 * KP + s0 * 8) * 2;
    const char* gB1 = gB + ((size_t)r1 * KP + s1 * 8) * 2;
    char* lA = lds;
    char* lB = lds + 8192;

    f32x4 acc00 = {0.f,0.f,0.f,0.f}, acc01 = {0.f,0.f,0.f,0.f};
    f32x4 acc10 = {0.f,0.f,0.f,0.f}, acc11 = {0.f,0.f,0.f,0.f};

    f16x8 ra0 = gather_A(X2, a, mrow0, s0 * 4);
    f16x8 ra1 = gather_A(X2, a, mrow1, s1 * 4);
    f16x8 rb0 = *(const f16x8*)(gB0);
    f16x8 rb1 = *(const f16x8*)(gB1);

    const int arow0 = wm * 32 + (l & 15), arow1 = arow0 + 16;
    const int brow0 = wn * 32 + (l & 15), brow1 = brow0 + 16;
    const int kq = l >> 4;

    for (int kk = 0; kk < KP; kk += 64) {
        __syncthreads();                     // previous frag reads complete
        *(f16x8*)(lA + q0 * 16) = ra0;
        *(f16x8*)(lA + q1 * 16) = ra1;
        *(f16x8*)(lB + q0 * 16) = rb0;
        *(f16x8*)(lB + q1 * 16) = rb1;
        __syncthreads();
        if (kk + 64 < KP) {                  // next-panel gather/loads in MFMA shadow
            const int jgb = (kk + 64) >> 1;
            ra0 = gather_A(X2, a, mrow0, jgb + s0 * 4);
            ra1 = gather_A(X2, a, mrow1, jgb + s1 * 4);
            rb0 = *(const f16x8*)(gB0 + (kk + 64) * 2);
            rb1 = *(const f16x8*)(gB1 + (kk + 64) * 2);
        }
#pragma unroll
        for (int ks = 0; ks < 2; ++ks) {
            const int kb = ks * 4 + kq;
            f16x8 a0 = *(const f16x8*)(lA + arow0 * 128 + ((kb ^ (arow0 & 7)) << 4));
            f16x8 a1 = *(const f16x8*)(lA + arow1 * 128 + ((kb ^ (arow1 & 7)) << 4));
            f16x8 b0 = *(const f16x8*)(lB + brow0 * 128 + ((kb ^ (brow0 & 7)) << 4));
            f16x8 b1 = *(const f16x8*)(lB + brow1 * 128 + ((kb ^ (brow1 & 7)) << 4));
            acc00 = __builtin_amdgcn_mfma_f32_16x16x32_f16(a0, b0, acc00, 0, 0, 0);
            acc01 = __builtin_amdgcn_mfma_f32_16x16x32_f16(a0, b1, acc01, 0, 0, 0);
            acc10 = __builtin_amdgcn_mfma_f32_16x16x32_f16(a1, b0, acc10, 0, 0, 0);
            acc11 = __builtin_amdgcn_mfma_f32_16x16x32_f16(a1, b1, acc11, 0, 0, 0);
        }
    }

    // epilogue: C/D layout col=l&15, row=(l>>4)*4+reg. Per lane, the 16 elements
    // span exactly 2 g's (g0, g0+2) x 2 ncols -> 4 inverse-norm values from S.
    const int mbase = bm * 64 + wm * 32;
    const int nbase = bn * 64 + wn * 32;
    const int ncol0 = nbase + (l & 15);
    const int ncol1 = ncol0 + 16;
    const int g0    = (mbase >> 3) + (kq >> 1);
    const float inv00 = inv_norm(S, g0,     ncol0);
    const float inv01 = inv_norm(S, g0,     ncol1);
    const float inv10 = inv_norm(S, g0 + 2, ncol0);
    const float inv11 = inv_norm(S, g0 + 2, ncol1);

#pragma unroll
    for (int mi = 0; mi < 2; ++mi) {
#pragma unroll
        for (int ni = 0; ni < 2; ++ni) {
            f32x4 v = (mi == 0) ? ((ni == 0) ? acc00 : acc01)
                                : ((ni == 0) ? acc10 : acc11);
            const float invv = (mi == 0) ? ((ni == 0) ? inv00 : inv01)
                                         : ((ni == 0) ? inv10 : inv11);
            const int ncol = (ni == 0) ? ncol0 : ncol1;
#pragma unroll
            for (int reg = 0; reg < 4; ++reg) {
                const int mrow = mbase + mi * 16 + kq * 4 + reg;
                if (mrow < MROWS) {
                    const int g = mrow >> 3, b = mrow & 7;
                    const int p = (g << 10) + ncol;
                    if (p < length)
                        out[(size_t)b * length + p] = v[reg] * invv;
                }
            }
        }
    }
}

// Last-resort fallback (ws too small): on-the-fly trig gather.
__global__ void icqt_gather_fallback(const float* __restrict__ X, float* __restrict__ out,
                                     CqtArgs a, int length) {
    const int p = blockIdx.x * blockDim.x + threadIdx.x;
    if (p >= length) return;
    float acc[NB];
#pragma unroll
    for (int b = 0; b < NB; ++b) acc[b] = 0.0f;
    float nrm = 0.0f;
    int fhi = p >> 10;
    if (fhi > NFRAMES - 1) fhi = NFRAMES - 1;
    const float2* X2 = reinterpret_cast<const float2*>(X);
    for (int k = 0; k < NBINS; ++k) {
        const int L = a.wl[k];
        int flo = (p - L + HOP) >> 10;
        if (flo < 0) flo = 0;
        for (int f = flo; f <= fhi; ++f) {
            const int t = p - (f << 10);
            if (t < L) {
                float tf = (float)t;
                float ang = a.omega[k] * tf;
                float s = sinf(ang), c = cosf(ang);
                float w = 0.5f - 0.5f * cosf(6.28318530717958647692f * tf * a.invL[k]);
                float bre = c * w, bim = s * w;
                nrm += w * w;
                const int base = k * NFRAMES + f;
#pragma unroll
                for (int b = 0; b < NB; ++b) {
                    float2 cv = X2[(size_t)b * (NBINS * NFRAMES) + base];
                    acc[b] += cv.x * bre - cv.y * bim;
                }
            }
        }
    }
    const float inv = 1.0f / ((nrm > 1e-10f) ? nrm : 1.0f);
#pragma unroll
    for (int b = 0; b < NB; ++b)
        out[(size_t)b * length + p] = acc[b] * inv;
}

extern "C" void kernel_launch(void* const* d_in, const int* in_sizes, int n_in,
                              void* d_out, int out_size, void* d_ws, size_t ws_size,
                              hipStream_t stream) {
    // Host geometry (deterministic; np.round = banker's via nearbyint)
    CqtArgs a;
    int cb[NBINS];
    const double SR = 44100.0;
    const double Q  = 1.0 / (std::exp2(1.0 / 12.0) - 1.0);
    int Ktot = 0;
    for (int k = 0; k < NBINS; ++k) {
        double f = 32.7 * std::exp2((double)k / 12.0);
        int L = (int)std::nearbyint(Q * SR / f);
        a.wl[k]    = L;
        cb[k]      = Ktot;
        a.omega[k] = (float)(2.0 * 3.14159265358979323846 * f / SR);
        a.invL[k]  = (float)(1.0 / (double)L);
        Ktot += 2 * ((L + 1023) / 1024);
    }
    a.Ktot = Ktot;
    for (int col = 0; col < KP; ++col) a.ct[col] = 0xFFFF;
    if (Ktot <= KP) {
        for (int k = 0; k < NBINS; ++k) {
            const int D2 = 2 * ((a.wl[k] + 1023) / 1024);
            for (int j = 0; j < D2; ++j)
                a.ct[cb[k] + j] = (unsigned short)(k | ((j >> 1) << 7) | ((j & 1) << 12));
        }
    }

    const int length = out_size / NB;            // 283800
    const float* X = (const float*)d_in[0];
    float* out     = (float*)d_out;

    // ws layout: [ Bt f16 1024xKP ][ S f32 23*1024 ]  (~2.06 MB total)
    const size_t offB = 0;
    const size_t szB  = (size_t)1024 * KP * 2;           // 1,966,080
    const size_t offS = offB + szB;
    const size_t szS  = (size_t)SD * 1024 * 4;           //    94,208
    const size_t need = offS + szS;

    if (Ktot > KP || a.wl[0] > SD * 1024 || ws_size < need) {
        const int blocks = (length + 255) / 256;
        icqt_gather_fallback<<<blocks, 256, 0, stream>>>(X, out, a, length);
        return;
    }

    unsigned short* Bt = (unsigned short*)((char*)d_ws + offB);
    float*          S  = (float*)((char*)d_ws + offS);

    build_bt_s<<<dim3(ALL_BLOCKS), 256, 0, stream>>>(Bt, S, a);
    gemm_icqt<<<dim3(MPAD / 64, 1024 / 64), 256, 0, stream>>>(
        (const float2*)X, Bt, S, out, length, a);
}

// Round 11
// 46.350 us; speedup vs baseline: 2.3963x; 1.4801x over previous
//
#include <hip/hip_runtime.h>
#include <hip/hip_fp16.h>
#include <cmath>

#define NBINS   84
#define NFRAMES 256
#define HOP     1024
#define NB      8            // nb_samples * nb_channels
#define KP      960          // padded K (f16 columns of A / rows of B)
#define KPQ     (KP/8)       // 120 quads (4 cos/sin pairs) per row
#define GBLK    278          // number of 1024-sample output blocks
#define MROWS   (GBLK*NB)    // 2224 real rows
#define MPAD    2240         // 35*64
#define SD      23           // d-slices: max ceil(L/1024)

#define BM      64           // GEMM tile rows
#define BN      32           // GEMM tile cols

// builder regions (blocks of 256 threads)
#define BT_BLOCKS  480                      // 1024 r x 120 quads / 256
#define A_BLOCKS   (MPAD*KPQ/256)           // 1050: 2240 rows x 120 quads / 256
#define S_BLOCKS   92                       // 23*1024/256
#define ALL_BLOCKS (BT_BLOCKS + A_BLOCKS + S_BLOCKS)

typedef _Float16 f16x8 __attribute__((ext_vector_type(8)));
typedef float    f32x4 __attribute__((ext_vector_type(4)));

struct alignas(16) CqtArgs {
    unsigned short ct[KP];      // FIRST member, 16B-aligned: col -> k|d<<7|c<<12; 0xFFFF pad
    int   wl[NBINS];            // per-bin window length (descending)
    float omega[NBINS];         // 2*pi*f/SR
    float invL[NBINS];          // 1/wl
    int   Ktot;
};

// ---------------- fused builder: Bt + A + S (one kernel, 1622 blocks) --------
__global__ __launch_bounds__(256)
void build_all(unsigned short* __restrict__ Am, unsigned short* __restrict__ Bt,
               float* __restrict__ S, const float2* __restrict__ X2, CqtArgs a) {
    const int blk = blockIdx.x;
    const int tid = threadIdx.x;
    const float TWOPI = 6.28318530717958647692f;

    if (blk < BT_BLOCKS) {
        // Bt[r][2j]=cos(w_k t)*hann, [2j+1]=sin(w_k t)*hann; t=1024d+r; 4 pairs/thread
        const int idx  = blk * 256 + tid;        // < 1024*120
        const int r    = idx / KPQ;
        const int quad = idx - r * KPQ;
        const uint4 rr = *(const uint4*)(&a.ct[8 * quad]);
        const unsigned int recs[4] = { rr.x & 0xFFFFu, rr.y & 0xFFFFu,
                                       rr.z & 0xFFFFu, rr.w & 0xFFFFu };
        f16x8 v;
#pragma unroll
        for (int jj = 0; jj < 4; ++jj) {
            float vc = 0.f, vs = 0.f;
            const unsigned int rec = recs[jj];
            if (rec != 0xFFFFu) {
                const int k = rec & 0x7F, d = (rec >> 7) & 0x1F;
                const int t = (d << 10) + r;
                if (t < a.wl[k]) {
                    const float tf = (float)t;
                    const float w  = 0.5f - 0.5f * cosf(TWOPI * tf * a.invL[k]);
                    float s, c;
                    sincosf(a.omega[k] * tf, &s, &c);
                    vc = c * w; vs = s * w;
                }
            }
            v[2 * jj]     = (_Float16)vc;
            v[2 * jj + 1] = (_Float16)vs;
        }
        *(f16x8*)(Bt + (size_t)r * KP + 8 * quad) = v;
    } else if (blk < BT_BLOCKS + A_BLOCKS) {
        // A[row=(g*8+b)][2j]=Re X[b,k,g-d], [2j+1]=-Im X[b,k,g-d]; 4 pairs/thread
        const int idx  = (blk - BT_BLOCKS) * 256 + tid;   // < 2240*120
        const int row  = idx / KPQ;
        const int quad = idx - row * KPQ;
        const int g = row >> 3, b = row & 7;
        const bool rowok = (row < MROWS);
        const uint4 rr = *(const uint4*)(&a.ct[8 * quad]);
        const unsigned int recs[4] = { rr.x & 0xFFFFu, rr.y & 0xFFFFu,
                                       rr.z & 0xFFFFu, rr.w & 0xFFFFu };
        f16x8 v;
#pragma unroll
        for (int jj = 0; jj < 4; ++jj) {
            float re = 0.f, nim = 0.f;
            const unsigned int rec = recs[jj];
            const int k = rec & 0x7F, d = (rec >> 7) & 0x1F;
            const int f = g - d;
            if (rowok && rec != 0xFFFFu && f >= 0 && f < NFRAMES) {
                const float2 x = X2[((size_t)b * NBINS + k) * NFRAMES + f];
                re = x.x; nim = -x.y;
            }
            v[2 * jj]     = (_Float16)re;
            v[2 * jj + 1] = (_Float16)nim;
        }
        *(f16x8*)(Am + (size_t)row * KP + 8 * quad) = v;
    } else {
        // S[t] = sum_k [t < wl_k] hann_k(t)^2 ; wl descending -> break at first fail
        const int t = (blk - BT_BLOCKS - A_BLOCKS) * 256 + tid;   // t < 23552
        float sum = 0.f;
        for (int k = 0; k < NBINS; ++k) {
            if (t >= a.wl[k]) break;
            const float w = 0.5f - 0.5f * cosf(TWOPI * (float)t * a.invL[k]);
            sum += w * w;
        }
        S[t] = sum;
    }
}

// inverse norm: direct positive-term sum over d = max(0,g-255) .. min(g,22)
__device__ __forceinline__ float inv_norm(const float* __restrict__ S, int g, int ncol) {
    if (g >= GBLK) return 1.0f;
    const int lo = (g > NFRAMES - 1) ? (g - (NFRAMES - 1)) : 0;
    const int hi = g < (SD - 1) ? g : (SD - 1);
    float s = 0.f;
    for (int d = lo; d <= hi; ++d) s += S[(d << 10) + ncol];
    return (s > 1e-10f) ? 1.0f / s : 1.0f;
}

// GEMM: C[M=2240][N=1024] = A[M][K=960] * Bt[N][K]^T, f16 in / f32 acc.
// 64x32 tile (1120 blocks for occupancy), 4 waves (2m x 2n), each wave 32x16
// via 2x1 mfma_f32_16x16x32_f16 frags. LDS chunk-XOR swizzle; next-K panel
// loads issued in MFMA shadow (1-deep register prefetch).
__global__ __launch_bounds__(256)
void gemm_icqt(const unsigned short* __restrict__ Am, const unsigned short* __restrict__ Bt,
               const float* __restrict__ S, float* __restrict__ out, int length) {
    __shared__ __align__(16) char lds[12288];     // A: 64x64 f16 = 8KB, B: 32x64 = 4KB
    const int tid = threadIdx.x;
    const int l   = tid & 63;
    const int wid = tid >> 6;
    const int wm  = wid >> 1, wn = wid & 1;
    const int bm  = blockIdx.x, bn = blockIdx.y;

    // A staging: 512 chunks, 2/thread; B staging: 256 chunks, 1/thread
    const int q0 = tid,      q1 = tid + 256;
    const int r0 = q0 >> 3,  c0 = q0 & 7, s0 = c0 ^ (r0 & 7);
    const int r1 = q1 >> 3,  c1 = q1 & 7, s1 = c1 ^ (r1 & 7);
    const int r2 = tid >> 3, c2 = tid & 7, s2 = c2 ^ (r2 & 7);

    const char* gA = (const char*)Am + (size_t)(bm * BM) * KP * 2;
    const char* gB = (const char*)Bt + (size_t)(bn * BN) * KP * 2;
    const char* gA0 = gA + ((size_t)r0 * KP + s0 * 8) * 2;
    const char* gA1 = gA + ((size_t)r1 * KP + s1 * 8) * 2;
    const char* gB0 = gB + ((size_t)r2 * KP + s2 * 8) * 2;
    char* lA = lds;
    char* lB = lds + 8192;

    f32x4 acc0 = {0.f,0.f,0.f,0.f}, acc1 = {0.f,0.f,0.f,0.f};

    f16x8 ra0 = *(const f16x8*)(gA0);
    f16x8 ra1 = *(const f16x8*)(gA1);
    f16x8 rb  = *(const f16x8*)(gB0);

    const int arow0 = wm * 32 + (l & 15), arow1 = arow0 + 16;
    const int brow  = wn * 16 + (l & 15);
    const int kq = l >> 4;

    for (int kk = 0; kk < KP; kk += 64) {
        __syncthreads();                     // previous frag reads complete
        *(f16x8*)(lA + q0 * 16) = ra0;
        *(f16x8*)(lA + q1 * 16) = ra1;
        *(f16x8*)(lB + tid * 16) = rb;
        __syncthreads();
        if (kk + 64 < KP) {                  // next-panel loads in MFMA shadow
            ra0 = *(const f16x8*)(gA0 + (kk + 64) * 2);
            ra1 = *(const f16x8*)(gA1 + (kk + 64) * 2);
            rb  = *(const f16x8*)(gB0 + (kk + 64) * 2);
        }
#pragma unroll
        for (int ks = 0; ks < 2; ++ks) {
            const int kb = ks * 4 + kq;
            f16x8 a0 = *(const f16x8*)(lA + arow0 * 128 + ((kb ^ (arow0 & 7)) << 4));
            f16x8 a1 = *(const f16x8*)(lA + arow1 * 128 + ((kb ^ (arow1 & 7)) << 4));
            f16x8 b0 = *(const f16x8*)(lB + brow  * 128 + ((kb ^ (brow  & 7)) << 4));
            acc0 = __builtin_amdgcn_mfma_f32_16x16x32_f16(a0, b0, acc0, 0, 0, 0);
            acc1 = __builtin_amdgcn_mfma_f32_16x16x32_f16(a1, b0, acc1, 0, 0, 0);
        }
    }

    // epilogue: C/D layout col=l&15, row=(l>>4)*4+reg. Per lane: 2 g's, 1 ncol.
    const int mbase = bm * BM + wm * 32;
    const int ncol  = bn * BN + wn * 16 + (l & 15);
    const int g0    = (mbase >> 3) + (kq >> 1);
    const float inv0 = inv_norm(S, g0,     ncol);
    const float inv1 = inv_norm(S, g0 + 2, ncol);

#pragma unroll
    for (int mi = 0; mi < 2; ++mi) {
        const f32x4 v    = mi ? acc1 : acc0;
        const float invv = mi ? inv1 : inv0;
#pragma unroll
        for (int reg = 0; reg < 4; ++reg) {
            const int mrow = mbase + mi * 16 + kq * 4 + reg;
            if (mrow < MROWS) {
                const int g = mrow >> 3, b = mrow & 7;
                const int p = (g << 10) + ncol;
                if (p < length)
                    out[(size_t)b * length + p] = v[reg] * invv;
            }
        }
    }
}

// Last-resort fallback (ws too small): on-the-fly trig gather.
__global__ void icqt_gather_fallback(const float* __restrict__ X, float* __restrict__ out,
                                     CqtArgs a, int length) {
    const int p = blockIdx.x * blockDim.x + threadIdx.x;
    if (p >= length) return;
    float acc[NB];
#pragma unroll
    for (int b = 0; b < NB; ++b) acc[b] = 0.0f;
    float nrm = 0.0f;
    int fhi = p >> 10;
    if (fhi > NFRAMES - 1) fhi = NFRAMES - 1;
    const float2* X2 = reinterpret_cast<const float2*>(X);
    for (int k = 0; k < NBINS; ++k) {
        const int L = a.wl[k];
        int flo = (p - L + HOP) >> 10;
        if (flo < 0) flo = 0;
        for (int f = flo; f <= fhi; ++f) {
            const int t = p - (f << 10);
            if (t < L) {
                float tf = (float)t;
                float ang = a.omega[k] * tf;
                float s = sinf(ang), c = cosf(ang);
                float w = 0.5f - 0.5f * cosf(6.28318530717958647692f * tf * a.invL[k]);
                float bre = c * w, bim = s * w;
                nrm += w * w;
                const int base = k * NFRAMES + f;
#pragma unroll
                for (int b = 0; b < NB; ++b) {
                    float2 cv = X2[(size_t)b * (NBINS * NFRAMES) + base];
                    acc[b] += cv.x * bre - cv.y * bim;
                }
            }
        }
    }
    const float inv = 1.0f / ((nrm > 1e-10f) ? nrm : 1.0f);
#pragma unroll
    for (int b = 0; b < NB; ++b)
        out[(size_t)b * length + p] = acc[b] * inv;
}

extern "C" void kernel_launch(void* const* d_in, const int* in_sizes, int n_in,
                              void* d_out, int out_size, void* d_ws, size_t ws_size,
                              hipStream_t stream) {
    // Host geometry (deterministic; np.round = banker's via nearbyint)
    CqtArgs a;
    int cb[NBINS];
    const double SR = 44100.0;
    const double Q  = 1.0 / (std::exp2(1.0 / 12.0) - 1.0);
    int Ktot = 0;
    for (int k = 0; k < NBINS; ++k) {
        double f = 32.7 * std::exp2((double)k / 12.0);
        int L = (int)std::nearbyint(Q * SR / f);
        a.wl[k]    = L;
        cb[k]      = Ktot;
        a.omega[k] = (float)(2.0 * 3.14159265358979323846 * f / SR);
        a.invL[k]  = (float)(1.0 / (double)L);
        Ktot += 2 * ((L + 1023) / 1024);
    }
    a.Ktot = Ktot;
    for (int col = 0; col < KP; ++col) a.ct[col] = 0xFFFF;
    if (Ktot <= KP) {
        for (int k = 0; k < NBINS; ++k) {
            const int D2 = 2 * ((a.wl[k] + 1023) / 1024);
            for (int j = 0; j < D2; ++j)
                a.ct[cb[k] + j] = (unsigned short)(k | ((j >> 1) << 7) | ((j & 1) << 12));
        }
    }

    const int length = out_size / NB;            // 283800
    const float* X = (const float*)d_in[0];
    float* out     = (float*)d_out;

    // ws layout: [ A f16 MPADxKP ][ Bt f16 1024xKP ][ S f32 23*1024 ]
    const size_t offA = 0;
    const size_t szA  = (size_t)MPAD * KP * 2;           // 4,300,800
    const size_t offB = offA + szA;
    const size_t szB  = (size_t)1024 * KP * 2;           // 1,966,080
    const size_t offS = offB + szB;
    const size_t szS  = (size_t)SD * 1024 * 4;           //    94,208
    const size_t need = offS + szS;

    if (Ktot > KP || a.wl[0] > SD * 1024 || ws_size < need) {
        const int blocks = (length + 255) / 256;
        icqt_gather_fallback<<<blocks, 256, 0, stream>>>(X, out, a, length);
        return;
    }

    unsigned short* Am = (unsigned short*)((char*)d_ws + offA);
    unsigned short* Bt = (unsigned short*)((char*)d_ws + offB);
    float*          S  = (float*)((char*)d_ws + offS);

    build_all<<<dim3(ALL_BLOCKS), 256, 0, stream>>>(Am, Bt, S, (const float2*)X, a);
    gemm_icqt<<<dim3(MPAD / BM, 1024 / BN), 256, 0, stream>>>(Am, Bt, S, out, length);
}